// Round 1
// baseline (430.656 us; speedup 1.0000x reference)
//
#include <hip/hip_runtime.h>
#include <stdint.h>

#define B_GRAPHS 256
#define NPER     512
#define EPER     4096
#define DDIM     64
#define KKEEP    1024
#define HIDDEN   256
#define JT       8          // hidden-tile width
#define NTILE    (HIDDEN/JT)

// Kernel A: one block per graph. Compute per-node projections A=h@W1a+b1,
// B=h@W1b in JT-wide hidden tiles in LDS, immediately consume them for all
// 4096 edges of the graph, accumulate per-edge scores in registers.
__global__ __launch_bounds__(1024) void scores_kernel(
    const float* __restrict__ h, const float* __restrict__ W1,
    const float* __restrict__ b1, const float* __restrict__ W2,
    const float* __restrict__ b2, const int* __restrict__ edge0,
    const int* __restrict__ edge1, float* __restrict__ sc_out)
{
  __shared__ float At[NPER * 9];   // stride 9 floats: odd stride -> LDS banks spread
  __shared__ float Bt[NPER * 9];
  const int t = threadIdx.x;
  const int b = blockIdx.x;
  const int mat = t >> 9;          // 0: A-projection threads, 1: B-projection
  const int n   = t & (NPER - 1);

  // h row for this thread's node, kept in registers for all 32 tiles
  const float4* hrow = (const float4*)(h + ((size_t)b * NPER + n) * DDIM);
  float hreg[DDIM];
#pragma unroll
  for (int i = 0; i < 16; ++i) {
    float4 v = hrow[i];
    hreg[4*i+0] = v.x; hreg[4*i+1] = v.y; hreg[4*i+2] = v.z; hreg[4*i+3] = v.w;
  }

  // this thread's 4 edges (local node ids), score accumulators in registers
  int er[4], ec[4];
  float eacc[4];
#pragma unroll
  for (int i = 0; i < 4; ++i) {
    const size_t e = (size_t)b * EPER + t + i * 1024;
    er[i] = edge0[e] & (NPER - 1);
    ec[i] = edge1[e] & (NPER - 1);
    eacc[i] = 0.f;
  }

  const int matu = __builtin_amdgcn_readfirstlane(mat);   // wave-uniform -> s_loads for W1
  const float* __restrict__ W1m = W1 + (size_t)matu * 64 * HIDDEN;  // rows 0..63 (A) / 64..127 (B)
  float* const dst = matu ? Bt : At;

  for (int jt = 0; jt < NTILE; ++jt) {
    const int j0 = jt * JT;
    float a8[JT];
#pragma unroll
    for (int jj = 0; jj < JT; ++jj) a8[jj] = matu ? 0.f : b1[j0 + jj];
#pragma unroll
    for (int d = 0; d < DDIM; ++d) {
      const float hval = hreg[d];
#pragma unroll
      for (int jj = 0; jj < JT; ++jj)
        a8[jj] = fmaf(hval, W1m[d * HIDDEN + j0 + jj], a8[jj]);
    }
#pragma unroll
    for (int jj = 0; jj < JT; ++jj) dst[n * 9 + jj] = a8[jj];
    __syncthreads();

    float w2r[JT];
#pragma unroll
    for (int jj = 0; jj < JT; ++jj) w2r[jj] = W2[j0 + jj];   // uniform -> s_load
#pragma unroll
    for (int i = 0; i < 4; ++i) {
      float part = 0.f;
#pragma unroll
      for (int jj = 0; jj < JT; ++jj) {
        float hid = At[er[i] * 9 + jj] + Bt[ec[i] * 9 + jj];
        part = fmaf(fmaxf(hid, 0.f), w2r[jj], part);
      }
      eacc[i] += part;
    }
    __syncthreads();   // protect LDS tiles before next tile's writes
  }

  const float b2v = b2[0];
#pragma unroll
  for (int i = 0; i < 4; ++i)
    sc_out[(size_t)b * EPER + t + i * 1024] = eacc[i] + b2v;
}

// Kernel B: per-graph bitonic sort of (score desc, idx asc) packed u64 keys,
// write causal/spurious edge weights, build node mask from kept edges,
// masked-sum h -> causal_rep. One block per graph.
__global__ __launch_bounds__(1024) void sort_kernel(
    const float* __restrict__ sc, const int* __restrict__ edge0,
    const int* __restrict__ edge1, const float* __restrict__ h,
    float* __restrict__ out_rep, float* __restrict__ out_cw,
    float* __restrict__ out_sw)
{
  __shared__ unsigned long long keys[EPER];  // 32 KB
  __shared__ int mask[NPER];                 // 2 KB
  __shared__ float red[16 * 64];             // 4 KB
  const int t = threadIdx.x;
  const int b = blockIdx.x;

  if (t < NPER) mask[t] = 0;

  // build keys: ascending u64 order == (score desc, edge idx asc)
#pragma unroll
  for (int i = 0; i < 4; ++i) {
    const int e = t + i * 1024;
    const float s = sc[(size_t)b * EPER + e];
    unsigned u  = __float_as_uint(s);
    unsigned fk = (u & 0x80000000u) ? ~u : (u | 0x80000000u);  // ascending-orderable
    unsigned dk = ~fk;                                          // descending
    keys[e] = ((unsigned long long)dk << 32) | (unsigned)e;
  }

  for (int k = 2; k <= EPER; k <<= 1) {
    for (int j = k >> 1; j > 0; j >>= 1) {
      __syncthreads();
#pragma unroll
      for (int i = 0; i < 4; ++i) {
        const int p = t + i * 1024;
        const int l = p ^ j;
        if (l > p) {
          const unsigned long long a = keys[p], c = keys[l];
          const bool up = ((p & k) == 0);
          if (up ? (a > c) : (a < c)) { keys[p] = c; keys[l] = a; }
        }
      }
    }
  }
  __syncthreads();

  // sorted outputs: positions [0,K) -> causal weights, [K,E) -> -score
#pragma unroll
  for (int i = 0; i < 4; ++i) {
    const int p = t + i * 1024;
    const unsigned long long key = keys[p];
    const unsigned fk = ~(unsigned)(key >> 32);
    const unsigned u  = (fk & 0x80000000u) ? (fk & 0x7fffffffu) : ~fk;  // exact bits back
    const float s = __uint_as_float(u);
    if (p < KKEEP) out_cw[(size_t)b * KKEEP + p] = s;
    else           out_sw[(size_t)b * (EPER - KKEEP) + (p - KKEEP)] = -s;
  }

  // node mask from kept edges (blockDim == KKEEP, so thread t owns position t)
  {
    const int e = (int)(keys[t] & 0xffffffffu);
    const size_t eg = (size_t)b * EPER + e;
    mask[edge0[eg] & (NPER - 1)] = 1;   // same-value LDS races are benign
    mask[edge1[eg] & (NPER - 1)] = 1;
  }
  __syncthreads();

  // masked segment sum: lanes = dims (coalesced h reads), 16 node-groups
  {
    const int d = t & 63, g = t >> 6;
    float s = 0.f;
    for (int nn = g; nn < NPER; nn += 16)
      if (mask[nn]) s += h[((size_t)b * NPER + nn) * DDIM + d];
    red[g * 64 + d] = s;
  }
  __syncthreads();
  if (t < 64) {
    float tot = 0.f;
#pragma unroll
    for (int g = 0; g < 16; ++g) tot += red[g * 64 + t];
    out_rep[(size_t)b * DDIM + t] = tot;
  }
}

extern "C" void kernel_launch(void* const* d_in, const int* in_sizes, int n_in,
                              void* d_out, int out_size, void* d_ws, size_t ws_size,
                              hipStream_t stream) {
  const float* h    = (const float*)d_in[0];
  const float* W1   = (const float*)d_in[1];
  const float* b1   = (const float*)d_in[2];
  const float* W2   = (const float*)d_in[3];
  const float* b2   = (const float*)d_in[4];
  const int*   eidx = (const int*)d_in[5];
  const int* edge0 = eidx;
  const int* edge1 = eidx + (size_t)B_GRAPHS * EPER;

  float* sc = (float*)d_ws;                 // 4 MB scratch for scores

  float* out     = (float*)d_out;
  float* out_rep = out;                                   // 256*64
  float* out_cw  = out + B_GRAPHS * DDIM;                 // 256*1024
  float* out_sw  = out_cw + (size_t)B_GRAPHS * KKEEP;     // 256*3072

  scores_kernel<<<B_GRAPHS, 1024, 0, stream>>>(h, W1, b1, W2, b2, edge0, edge1, sc);
  sort_kernel<<<B_GRAPHS, 1024, 0, stream>>>(sc, edge0, edge1, h, out_rep, out_cw, out_sw);
}